// Round 5
// baseline (258.517 us; speedup 1.0000x reference)
//
#include <hip/hip_runtime.h>

#define TT   256    // timesteps
#define FF   23     // lab features
#define HH   100    // hidden
#define NROW 4      // batch rows per workgroup
#define NTHR 256    // 4 waves, 1 per SIMD
#define NWG  256    // 1024 / NROW -> one wg per CU

typedef unsigned int  u32;
typedef unsigned short u16;
typedef __attribute__((ext_vector_type(8))) short short8;  // 8 bf16 in 4 VGPRs
typedef __attribute__((ext_vector_type(4))) float f32x4;

__device__ __forceinline__ u16 f2bf(float f){           // RTNE f32->bf16
  u32 u = __float_as_uint(f);
  u += 0x7fffu + ((u >> 16) & 1u);
  return (u16)(u >> 16);
}
__device__ __forceinline__ float fsig(float x){
  return __builtin_amdgcn_rcpf(1.0f + __expf(-x));
}
__device__ __forceinline__ float ftanh(float x){
  return 1.0f - 2.0f * __builtin_amdgcn_rcpf(__expf(2.0f * x) + 1.0f);
}

// LDS layouts (bf16):
//  h/c: idx(b,k) = (k>>5)*128 + b*32 + ((k>>3)&3)*8 + (k&7)   [kf][b][q4][i]
//  x:   sXall[t*128 + b*32 + k]; k=24..27 carry the h[96..99] fold (written
//       each step by wave 2's tile-1 lanes nl<4)
// Batch row b sits at MFMA tile-row 4b -> C/D reg 0 of every lane is real.
// Each wave computes TWO N=16 column tiles: j = w*16+nl and j2 = 64+w*16+nl
// (wave 3 tile1 = cols 112..127, all pad -> skipped). A-frags (h,c,x) are
// shared by both tiles -> LDS reads stay 8/wave/step (32/CU vs 56 before).

__global__ __launch_bounds__(NTHR, 1) void tlstm6(
    const float* __restrict__ x_lab,  const float* __restrict__ t_lab,
    const float* __restrict__ x_state,const float* __restrict__ W_x,
    const float* __restrict__ W_h,    const float* __restrict__ b_lstm,
    const float* __restrict__ W_d,    const float* __restrict__ b_d,
    const float* __restrict__ W_state,const float* __restrict__ b_state,
    const float* __restrict__ W_fc,   const float* __restrict__ b_fc,
    float* __restrict__ out)
{
  __shared__ __align__(16) short sXall[TT * 128]; // 64 KB: x for ALL steps
  __shared__ __align__(16) short sHC[2][2][512];  // [buf][h=0/c=1]
  __shared__ __align__(16) float sDec[TT * NROW]; // [t*4 + b]
  __shared__ __align__(16) float sHF[NROW][128];  // fp32 h_final

  const int tid  = threadIdx.x;
  const int lane = tid & 63;
  const int w    = tid >> 6;        // wave 0..3
  const int nl   = lane & 15;
  const int q4   = lane >> 4;
  const int b0   = blockIdx.x * NROW;
  const int j0   = w * 16 + nl;          // tile0 column (0..63, all real)
  const int j1   = 64 + w * 16 + nl;     // tile1 column (64..127; real <100)
  const bool jr1 = (j1 < HH);
  const bool has2 = (w < 3);             // wave 3: tile1 all pad -> skip

  // ---- zero h/c state buffers ----
  for (int i = tid; i < 1024; i += NTHR) ((u32*)sHC)[i] = 0u;

  // ---- stage ENTIRE x sequence (bf16, frag layout, pads zeroed) ----
  for (int e = tid; e < TT * 128; e += NTHR) {
    int t = e >> 7, inner = e & 127, r = inner >> 5, f = inner & 31;
    float x = (f < FF) ? x_lab[((b0 + r)*TT + t)*FF + f] : 0.f;
    sXall[e] = (short)f2bf(x);
  }
  // ---- decay table ----
  for (int e = tid; e < TT * NROW; e += NTHR) {
    int t = e >> 2, r = e & 3;
    sDec[e] = 1.0f / logf(2.718281828459045f + t_lab[(b0 + r)*TT + t]);
  }

  // ---- persistent weight fragments for both tiles ----
  short8 wh[2][4][3], wd[2][4], wx[2][4];
#pragma unroll
  for (int tl = 0; tl < 2; ++tl) {
    const int jj = tl ? j1 : j0;
    const bool jv = tl ? jr1 : true;
#pragma unroll
    for (int g = 0; g < 4; ++g)
#pragma unroll
      for (int kf = 0; kf < 3; ++kf) {
        short8 v;
#pragma unroll
        for (int i = 0; i < 8; ++i) {
          int k = kf*32 + q4*8 + i;                 // k <= 95: always real
          v[i] = (short)(jv ? f2bf(W_h[k*400 + g*HH + jj]) : 0);
        }
        wh[tl][g][kf] = v;
      }
#pragma unroll
    for (int kf = 0; kf < 4; ++kf) {
      short8 v;
#pragma unroll
      for (int i = 0; i < 8; ++i) {
        int k = kf*32 + q4*8 + i;
        v[i] = (short)((k < HH && jv) ? f2bf(W_d[k*HH + jj]) : 0);
      }
      wd[tl][kf] = v;
    }
#pragma unroll
    for (int g = 0; g < 4; ++g) {
      short8 v;
#pragma unroll
      for (int i = 0; i < 8; ++i) {
        int k = q4*8 + i;
        float x = 0.f;
        if (jv) {
          if (k < FF)                 x = W_x[k*400 + g*HH + jj];
          else if (k >= 24 && k < 28) x = W_h[(96 + (k-24))*400 + g*HH + jj]; // h-fold
        }
        v[i] = (short)f2bf(x);
      }
      wx[tl][g] = v;
    }
  }

  float bl[2][4], bd[2];
#pragma unroll
  for (int g = 0; g < 4; ++g) {
    bl[0][g] = b_lstm[g*HH + j0];
    bl[1][g] = jr1 ? b_lstm[g*HH + j1] : 0.f;
  }
  bd[0] = b_d[j0];
  bd[1] = jr1 ? b_d[j1] : 0.f;

  __syncthreads();

  const bool rdr  = ((nl & 3) == 0);          // A-frag reader lanes
  const int rbase = (nl >> 2)*32 + q4*8;
  const int wi0   = (j0 >> 5)*128 + q4*32 + ((j0 >> 3) & 3)*8 + (j0 & 7);
  const int wi1   = (j1 >> 5)*128 + q4*32 + ((j1 >> 3) & 3)*8 + (j1 & 7);

  short8 ha[3] = {}, ca[4] = {}, xa = {};     // stay 0 in non-reader lanes
  float cm0 = 0.f, cm1 = 0.f;                 // fp32 master cell (b=q4)
  float hl0 = 0.f, hl1 = 0.f;

  const f32x4 zv = {0.f, 0.f, 0.f, 0.f};

  for (int t = 0; t < TT; ++t) {
    const short* hb = sHC[t & 1][0];
    const short* cb = sHC[t & 1][1];
    if (rdr) {
      xa = *(const short8*)(sXall + t*128 + rbase);
#pragma unroll
      for (int kf = 0; kf < 4; ++kf) ca[kf] = *(const short8*)(cb + kf*128 + rbase);
#pragma unroll
      for (int kf = 0; kf < 3; ++kf) ha[kf] = *(const short8*)(hb + kf*128 + rbase);
    }
    float dec = sDec[t*4 + q4];

    // ---- tile0 ----
    f32x4 d00 = {bd[0], bd[0], bd[0], bd[0]}, d01 = zv;
    d00 = __builtin_amdgcn_mfma_f32_16x16x32_bf16(ca[0], wd[0][0], d00, 0, 0, 0);
    d01 = __builtin_amdgcn_mfma_f32_16x16x32_bf16(ca[1], wd[0][1], d01, 0, 0, 0);
    d00 = __builtin_amdgcn_mfma_f32_16x16x32_bf16(ca[2], wd[0][2], d00, 0, 0, 0);
    d01 = __builtin_amdgcn_mfma_f32_16x16x32_bf16(ca[3], wd[0][3], d01, 0, 0, 0);
    f32x4 a00[4], a01[4];
#pragma unroll
    for (int g = 0; g < 4; ++g) {
      f32x4 b = {bl[0][g], bl[0][g], bl[0][g], bl[0][g]};
      a00[g] = __builtin_amdgcn_mfma_f32_16x16x32_bf16(xa, wx[0][g], b, 0, 0, 0);
      a01[g] = __builtin_amdgcn_mfma_f32_16x16x32_bf16(ha[0], wh[0][g][0], zv,     0, 0, 0);
      a00[g] = __builtin_amdgcn_mfma_f32_16x16x32_bf16(ha[1], wh[0][g][1], a00[g], 0, 0, 0);
      a01[g] = __builtin_amdgcn_mfma_f32_16x16x32_bf16(ha[2], wh[0][g][2], a01[g], 0, 0, 0);
    }
    // ---- tile1 (skipped by wave 3) ----
    f32x4 d10 = zv, d11 = zv;
    f32x4 a10[4], a11[4];
    if (has2) {
      d10 = f32x4{bd[1], bd[1], bd[1], bd[1]};
      d10 = __builtin_amdgcn_mfma_f32_16x16x32_bf16(ca[0], wd[1][0], d10, 0, 0, 0);
      d11 = __builtin_amdgcn_mfma_f32_16x16x32_bf16(ca[1], wd[1][1], zv,  0, 0, 0);
      d10 = __builtin_amdgcn_mfma_f32_16x16x32_bf16(ca[2], wd[1][2], d10, 0, 0, 0);
      d11 = __builtin_amdgcn_mfma_f32_16x16x32_bf16(ca[3], wd[1][3], d11, 0, 0, 0);
#pragma unroll
      for (int g = 0; g < 4; ++g) {
        f32x4 b = {bl[1][g], bl[1][g], bl[1][g], bl[1][g]};
        a10[g] = __builtin_amdgcn_mfma_f32_16x16x32_bf16(xa, wx[1][g], b, 0, 0, 0);
        a11[g] = __builtin_amdgcn_mfma_f32_16x16x32_bf16(ha[0], wh[1][g][0], zv,     0, 0, 0);
        a10[g] = __builtin_amdgcn_mfma_f32_16x16x32_bf16(ha[1], wh[1][g][1], a10[g], 0, 0, 0);
        a11[g] = __builtin_amdgcn_mfma_f32_16x16x32_bf16(ha[2], wh[1][g][2], a11[g], 0, 0, 0);
      }
    }

    // ---- pointwise (C/D reg 0 = batch row q4), two independent chains ----
    short* hn = sHC[(t + 1) & 1][0];
    short* cn = sHC[(t + 1) & 1][1];
    {
      float cs   = ftanh(d00[0] + d01[0]);
      float cadj = cm0 - cs + cs*dec;
      float ig = fsig (a00[0][0] + a01[0][0]);
      float fg = fsig (a00[1][0] + a01[1][0]);
      float gg = ftanh(a00[2][0] + a01[2][0]);
      float og = fsig (a00[3][0] + a01[3][0]);
      float cnv = fg*cadj + ig*gg;
      cm0 = cnv;
      float hv = og*ftanh(cnv);
      hl0 = hv;
      hn[wi0] = (short)f2bf(hv);
      cn[wi0] = (short)f2bf(cnv);
    }
    if (has2) {
      float cs   = ftanh(d10[0] + d11[0]);
      float cadj = cm1 - cs + cs*dec;
      float ig = fsig (a10[0][0] + a11[0][0]);
      float fg = fsig (a10[1][0] + a11[1][0]);
      float gg = ftanh(a10[2][0] + a11[2][0]);
      float og = fsig (a10[3][0] + a11[3][0]);
      float cnv = fg*cadj + ig*gg;
      cm1 = cnv;
      float hv = og*ftanh(cnv);
      hl1 = hv;
      hn[wi1] = (short)f2bf(hv);
      cn[wi1] = (short)f2bf(cnv);
      if (w == 2 && nl < 4 && t + 1 < TT)      // h[96..99] -> x-frag k=24..27
        sXall[(t + 1)*128 + q4*32 + 24 + nl] = (short)f2bf(hv);
    }

    __syncthreads();
  }

  // ---- epilogue ----
  sHF[q4][j0] = hl0;
  if (has2) sHF[q4][j1] = hl1;
  __syncthreads();

  if (tid < NROW) {
    const int bg = b0 + tid;
    float y0 = b_fc[0], y1 = b_fc[1];
    for (int k = 0; k < HH; ++k) {
      float hv = sHF[tid][k];
      y0 += hv * W_fc[2*k];
      y1 += hv * W_fc[2*k + 1];
    }
#pragma unroll
    for (int k = 0; k < 20; ++k) {
      float a = b_state[k];
#pragma unroll
      for (int s = 0; s < 6; ++s) a += x_state[bg*6 + s] * W_state[s*20 + k];
      y0 += a * W_fc[2*(HH + k)];
      y1 += a * W_fc[2*(HH + k) + 1];
    }
    float m = fmaxf(y0, y1);
    float e0 = __expf(y0 - m), e1 = __expf(y1 - m);
    float inv = 1.0f / (e0 + e1);
    out[bg*2 + 0] = e0 * inv;
    out[bg*2 + 1] = e1 * inv;
  }
}

extern "C" void kernel_launch(void* const* d_in, const int* in_sizes, int n_in,
                              void* d_out, int out_size, void* d_ws, size_t ws_size,
                              hipStream_t stream) {
  const float* x_lab   = (const float*)d_in[0];
  const float* t_lab   = (const float*)d_in[1];
  const float* x_state = (const float*)d_in[2];
  const float* W_x     = (const float*)d_in[3];
  const float* W_h     = (const float*)d_in[4];
  const float* b_lstm  = (const float*)d_in[5];
  const float* W_d     = (const float*)d_in[6];
  const float* b_d     = (const float*)d_in[7];
  const float* W_state = (const float*)d_in[8];
  const float* b_state = (const float*)d_in[9];
  const float* W_fc    = (const float*)d_in[10];
  const float* b_fc    = (const float*)d_in[11];
  float* outp = (float*)d_out;

  hipLaunchKernelGGL(tlstm6, dim3(NWG), dim3(NTHR), 0, stream,
                     x_lab, t_lab, x_state, W_x, W_h, b_lstm, W_d, b_d,
                     W_state, b_state, W_fc, b_fc, outp);
}